// Round 1
// baseline (21540.050 us; speedup 1.0000x reference)
//
#include <hip/hip_runtime.h>

#define SEQ   2048
#define BATCH 64
#define ISZ   512
#define HSZ   512
#define GC    1024            // gate cols kept (z,n)
#define MROWS (SEQ*BATCH)     // 131072

typedef _Float16 f16;
typedef _Float16 half8  __attribute__((ext_vector_type(8)));
typedef _Float16 half2v __attribute__((ext_vector_type(2)));
typedef float    f32x4  __attribute__((ext_vector_type(4)));

#if __has_builtin(__builtin_amdgcn_fdot2)
#define DOT2(a,b,c) __builtin_amdgcn_fdot2((a),(b),(c),false)
#else
#define DOT2(a,b,c) ((float)(a)[0]*(float)(b)[0] + (float)(a)[1]*(float)(b)[1] + (c))
#endif

#define TPAD 40    // LDS tile row stride (f16): 32 + 8 pad, keeps 16B alignment, 2-way banks (free)
#define CPAD 136   // epilogue LDS row stride (f16), 272B = 16B-aligned

// ---------------- Phase 1: x_proj = x @ W_ih[z,n]^T  (f16 MFMA) ----------------
__global__ __launch_bounds__(256, 1) void gemm_xproj(
    const float* __restrict__ x,      // [131072, 512]
    const float* __restrict__ wih,    // [1536, 512]
    const float* __restrict__ bias,   // [1536]
    f16* __restrict__ xp)             // [131072, 1024] f16
{
  __shared__ f16 lds[128*CPAD];       // 34816 B; K-loop uses first 2*128*TPAD
  f16* At = lds;
  f16* Bt = lds + 128*TPAD;

  const int bid  = blockIdx.x;
  const int nt   = bid & 7;           // 8 col tiles of 128
  const int mt   = bid >> 3;          // 1024 row tiles of 128
  const int t    = threadIdx.x;
  const int lane = t & 63;
  const int wave = t >> 6;
  const int wr = wave >> 1, wc = wave & 1;
  const int fm = lane & 15;
  const int fk = (lane >> 4) * 8;

  // staging: thread covers row sr, 16 consecutive floats at offset sk
  const int sr = t >> 1;
  const int sk = (t & 1) * 16;
  const float* xrow = x   + (size_t)(mt*128 + sr) * ISZ + sk;
  const float* wrow = wih + (size_t)(512 + nt*128 + sr) * ISZ + sk;

  f32x4 acc[4][4];
#pragma unroll
  for (int i=0;i<4;i++)
#pragma unroll
    for (int j=0;j<4;j++) acc[i][j] = (f32x4){0.f,0.f,0.f,0.f};

  for (int kb = 0; kb < ISZ/32; ++kb) {
    __syncthreads();
    const float4* xs = (const float4*)(xrow + kb*32);
    const float4* ws2 = (const float4*)(wrow + kb*32);
    float4 a0=xs[0], a1=xs[1], a2=xs[2], a3=xs[3];
    float4 b0=ws2[0], b1=ws2[1], b2=ws2[2], b3=ws2[3];
    union { f16 h[16]; f32x4 v[2]; } pa, pb;
    pa.h[0]=(f16)a0.x; pa.h[1]=(f16)a0.y; pa.h[2]=(f16)a0.z; pa.h[3]=(f16)a0.w;
    pa.h[4]=(f16)a1.x; pa.h[5]=(f16)a1.y; pa.h[6]=(f16)a1.z; pa.h[7]=(f16)a1.w;
    pa.h[8]=(f16)a2.x; pa.h[9]=(f16)a2.y; pa.h[10]=(f16)a2.z; pa.h[11]=(f16)a2.w;
    pa.h[12]=(f16)a3.x; pa.h[13]=(f16)a3.y; pa.h[14]=(f16)a3.z; pa.h[15]=(f16)a3.w;
    pb.h[0]=(f16)b0.x; pb.h[1]=(f16)b0.y; pb.h[2]=(f16)b0.z; pb.h[3]=(f16)b0.w;
    pb.h[4]=(f16)b1.x; pb.h[5]=(f16)b1.y; pb.h[6]=(f16)b1.z; pb.h[7]=(f16)b1.w;
    pb.h[8]=(f16)b2.x; pb.h[9]=(f16)b2.y; pb.h[10]=(f16)b2.z; pb.h[11]=(f16)b2.w;
    pb.h[12]=(f16)b3.x; pb.h[13]=(f16)b3.y; pb.h[14]=(f16)b3.z; pb.h[15]=(f16)b3.w;
    f32x4* ad = (f32x4*)(At + sr*TPAD + sk);
    f32x4* bd = (f32x4*)(Bt + sr*TPAD + sk);
    ad[0]=pa.v[0]; ad[1]=pa.v[1];
    bd[0]=pb.v[0]; bd[1]=pb.v[1];
    __syncthreads();

    half8 af[4], bf[4];
#pragma unroll
    for (int i=0;i<4;i++) af[i] = *(const half8*)(At + (wr*64 + i*16 + fm)*TPAD + fk);
#pragma unroll
    for (int j=0;j<4;j++) bf[j] = *(const half8*)(Bt + (wc*64 + j*16 + fm)*TPAD + fk);
#pragma unroll
    for (int i=0;i<4;i++)
#pragma unroll
      for (int j=0;j<4;j++)
        acc[i][j] = __builtin_amdgcn_mfma_f32_16x16x32_f16(af[i], bf[j], acc[i][j], 0, 0, 0);
  }

  __syncthreads();
  // epilogue: repack D frags (col=lane&15, row=(lane>>4)*4+r) through LDS for coalesced f16 stores
#pragma unroll
  for (int j=0;j<4;j++) {
    float bj = bias[512 + nt*128 + wc*64 + j*16 + fm];
#pragma unroll
    for (int i=0;i<4;i++) {
      int row0 = wr*64 + i*16 + (lane>>4)*4;
      int col  = wc*64 + j*16 + fm;
#pragma unroll
      for (int r=0;r<4;r++)
        lds[(row0 + r)*CPAD + col] = (f16)(acc[i][j][r] + bj);
    }
  }
  __syncthreads();
  {
    int row = t >> 1, ch = (t & 1) * 64;
    const f32x4* src = (const f32x4*)(lds + row*CPAD + ch);
    f32x4* dst = (f32x4*)(xp + (size_t)(mt*128 + row)*GC + nt*128 + ch);
#pragma unroll
    for (int u=0;u<8;++u) dst[u] = src[u];
  }
}

// ---------------- Phase 2: sequential scan, 4 blocks per batch element ----------------
// block bid = s*64 + b : batch b, j-slice s (j in [s*128,(s+1)*128)), W_z/W_n slice in VGPRs (f16)
__global__ __launch_bounds__(1024, 4) void gru_rec(
    const float* __restrict__ whh,    // [1536, 512]
    const f16* __restrict__ xp,       // [131072, 1024]
    float* __restrict__ out,          // outputs [2048,64,512] then h_final [64,512]
    int* __restrict__ flags)          // [256], zeroed before launch
{
  const int bid = blockIdx.x;
  const int s = bid >> 6;
  const int b = bid & 63;
  const int t = threadIdx.x;
  const int g  = t & 1;               // 0=z, 1=n
  const int jj = (t >> 1) & 127;
  const int q  = t >> 8;              // k-span [q*128, q*128+128)

  __shared__ __attribute__((aligned(16))) float hf[HSZ];
  __shared__ __attribute__((aligned(16))) f16   hh[HSZ];
  __shared__ float part[256][5];      // stride 5: conflict-free

  // resident weights: 128 f16 = 64 VGPRs
  half2v w[64];
  {
    const float4* wr4 = (const float4*)(whh + (size_t)(512 + g*512 + s*128 + jj)*HSZ + q*128);
#pragma unroll
    for (int i=0;i<32;i++) {
      float4 v = wr4[i];
      w[2*i]   = (half2v){(f16)v.x, (f16)v.y};
      w[2*i+1] = (half2v){(f16)v.z, (f16)v.w};
    }
  }

  if (t < HSZ) { hf[t] = 0.f; hh[t] = (f16)0.f; }

  const f16* xpb = xp + (size_t)b*GC + (g*512 + s*128 + jj);
  float xp_cur = 0.f, xp_nxt = 0.f;
  if (t < 256) xp_cur = (float)xpb[0];
  __syncthreads();

  for (int step = 0; step < SEQ; ++step) {
    // software-pipelined x_proj fetch for next step
    if (t < 256) {
      int nx = (step+1 < SEQ) ? step+1 : SEQ-1;
      xp_nxt = (float)xpb[(size_t)nx * BATCH * GC];
    }
    // partial dot over this thread's k-span
    const f32x4* hp4 = ((const f32x4*)hh) + q*16;
    float a0=0.f, a1=0.f, a2=0.f, a3=0.f;
#pragma unroll
    for (int i=0;i<16;i++) {
      union { f32x4 v; half2v h[4]; } u;
      u.v = hp4[i];                    // wave-uniform address -> LDS broadcast, conflict-free
      a0 = DOT2(w[4*i+0], u.h[0], a0);
      a1 = DOT2(w[4*i+1], u.h[1], a1);
      a2 = DOT2(w[4*i+2], u.h[2], a2);
      a3 = DOT2(w[4*i+3], u.h[3], a3);
    }
    part[t & 255][q] = (a0+a1)+(a2+a3);
    __syncthreads();

    if (t < 256) {
      float v = part[t][0]+part[t][1]+part[t][2]+part[t][3] + xp_cur;
      float other = __shfl_xor(v, 1);  // pair z (even lane) with n (odd lane)
      if (g == 0) {
        float z = 1.f/(1.f + __expf(-v));
        float n = tanhf(other);
        int j = s*128 + jj;
        float hn = (1.f - z)*n + z*hf[j];
        size_t o = ((size_t)step*BATCH + b)*HSZ + j;
        // d_out doubles as the h exchange buffer; agent-scope so partner XCDs see it
        __hip_atomic_store(out + o, hn, __ATOMIC_RELAXED, __HIP_MEMORY_SCOPE_AGENT);
        if (step == SEQ-1)
          out[(size_t)SEQ*BATCH*HSZ + (size_t)b*HSZ + j] = hn;
      }
    }
    __syncthreads();                   // barrier drains each wave's stores (vmcnt)
    if (t == 0) {
      __threadfence();
      __hip_atomic_store(flags + bid, step+1, __ATOMIC_RELEASE, __HIP_MEMORY_SCOPE_AGENT);
    }
    if (t < 4 && t != s) {             // 3 lanes poll 3 partners in parallel
      while (__hip_atomic_load(flags + t*64 + b, __ATOMIC_RELAXED, __HIP_MEMORY_SCOPE_AGENT) <= step) {}
    }
    __syncthreads();
    // restage full h_t for next step
    {
      float* hrow = out + ((size_t)step*BATCH + b)*HSZ;
      if (t < HSZ) {
        float v = __hip_atomic_load(hrow + t, __ATOMIC_RELAXED, __HIP_MEMORY_SCOPE_AGENT);
        hf[t] = v;
        hh[t] = (f16)v;
      }
    }
    xp_cur = xp_nxt;
    __syncthreads();
  }
}

extern "C" void kernel_launch(void* const* d_in, const int* in_sizes, int n_in,
                              void* d_out, int out_size, void* d_ws, size_t ws_size,
                              hipStream_t stream) {
  const float* x    = (const float*)d_in[0];
  const float* wih  = (const float*)d_in[1];
  const float* whh  = (const float*)d_in[2];
  const float* bias = (const float*)d_in[3];
  float* out = (float*)d_out;
  f16* xp    = (f16*)d_ws;                                   // 268,435,456 B
  int* flags = (int*)((char*)d_ws + (size_t)MROWS*GC*sizeof(f16));

  hipMemsetAsync(flags, 0, 256*sizeof(int), stream);
  hipLaunchKernelGGL(gemm_xproj, dim3((MROWS/128)*(GC/128)), dim3(256), 0, stream,
                     x, wih, bias, xp);

  const float* whh_a = whh; const f16* xp_a = xp; float* out_a = out; int* flags_a = flags;
  void* args[4] = { &whh_a, &xp_a, &out_a, &flags_a };
  hipLaunchCooperativeKernel((void*)gru_rec, dim3(256), dim3(1024), args, 0, stream);
}